// Round 1
// baseline (534.137 us; speedup 1.0000x reference)
//
#include <hip/hip_runtime.h>
#include <cstdint>
#include <cstddef>

#define NN 512
#define BB 64
#define MM 256
#define NB (NN*BB)          // 32768 elems per (chain) signal plane, layout [node][batch]
#define ZT 1e-9f
#define CAP 16384           // CSR capacity (expected nnz ~6.2K / ~7.9K)

// ---------------- CSR build: one wave per row ----------------
__global__ __launch_bounds__(256) void k_csr_count(const float* __restrict__ S,
                                                   int* __restrict__ sp_cnt,
                                                   int* __restrict__ s_cnt) {
  int wid = (blockIdx.x * 256 + threadIdx.x) >> 6;
  int lane = threadIdx.x & 63;
  if (wid >= NN) return;
  int m = wid;
  int csp = 0, cs = 0;
  for (int ch = 0; ch < NN / 64; ++ch) {
    int n = ch * 64 + lane;
    float s = S[(size_t)m * NN + n];
    bool ps  = (s != 0.0f);
    bool psp = ((fabsf(s) + ((m == n) ? 1.0f : 0.0f)) > ZT) && !((m >= MM) && (n >= MM));
    csp += __popcll(__ballot(psp));
    cs  += __popcll(__ballot(ps));
  }
  if (lane == 0) { sp_cnt[m] = csp; s_cnt[m] = cs; }
}

__global__ void k_prefix(int* __restrict__ sp_ptr, int* __restrict__ s_ptr,
                         const int* __restrict__ sp_cnt, const int* __restrict__ s_cnt) {
  int lane = threadIdx.x;  // 64 threads, one wave
  int c0[8], c1[8]; int t0 = 0, t1 = 0;
  for (int i = 0; i < 8; ++i) {
    c0[i] = sp_cnt[lane * 8 + i]; t0 += c0[i];
    c1[i] = s_cnt[lane * 8 + i];  t1 += c1[i];
  }
  int i0 = t0, i1 = t1;
  for (int d = 1; d < 64; d <<= 1) {
    int x0 = __shfl_up(i0, d), x1 = __shfl_up(i1, d);
    if (lane >= d) { i0 += x0; i1 += x1; }
  }
  int e0 = i0 - t0, e1 = i1 - t1;
  for (int i = 0; i < 8; ++i) {
    sp_ptr[lane * 8 + i] = e0; e0 += c0[i];
    s_ptr[lane * 8 + i]  = e1; e1 += c1[i];
  }
  if (lane == 63) { sp_ptr[NN] = e0; s_ptr[NN] = e1; }
}

__global__ __launch_bounds__(256) void k_csr_fill(const float* __restrict__ S,
    const int* __restrict__ sp_ptr, const int* __restrict__ s_ptr,
    int* __restrict__ sp_cols, int* __restrict__ sp_rows,
    int* __restrict__ s_cols, int* __restrict__ s_rows, float* __restrict__ s_vals) {
  int wid = (blockIdx.x * 256 + threadIdx.x) >> 6;
  int lane = threadIdx.x & 63;
  if (wid >= NN) return;
  int m = wid;
  int bsp = sp_ptr[m], bs = s_ptr[m];
  unsigned long long lt = (1ull << lane) - 1ull;
  for (int ch = 0; ch < NN / 64; ++ch) {
    int n = ch * 64 + lane;
    float s = S[(size_t)m * NN + n];
    bool ps  = (s != 0.0f);
    bool psp = ((fabsf(s) + ((m == n) ? 1.0f : 0.0f)) > ZT) && !((m >= MM) && (n >= MM));
    unsigned long long msp = __ballot(psp), ms = __ballot(ps);
    if (psp) { int p = bsp + __popcll(msp & lt); if (p < CAP) { sp_cols[p] = n; sp_rows[p] = m; } }
    if (ps)  { int p = bs  + __popcll(ms  & lt); if (p < CAP) { s_cols[p] = n; s_rows[p] = m; s_vals[p] = s; } }
    bsp += __popcll(msp); bs += __popcll(ms);
  }
}

// ---------------- x transpose: (B,N) -> (N,B) ----------------
__global__ __launch_bounds__(256) void k_transpose(const float* __restrict__ x,
                                                   float* __restrict__ xt) {
  int tid = blockIdx.x * 256 + threadIdx.x;   // 0..32767
  int n = tid >> 6, b = tid & 63;
  xt[tid] = x[(size_t)b * NN + n];
}

// ---------------- sparse chain step ----------------
// zout[c][m][b] = sum_n Wplane(c,k)[m,n] * zin[sel][n][b]
// Wdense != null : weights gathered from plane ((f*3+k)*G+g) of wEV (pattern CSR)
// Wdense == null : weights = svals[j] (CSR of S)
// batch b = lane (64). One wg = 4 waves; wave owns rows [r0,r1).
__global__ __launch_bounds__(256) void k_ev_step(
    const float* __restrict__ Wdense, const float* __restrict__ svals,
    const int* __restrict__ row_ptr, const int* __restrict__ cols,
    const int* __restrict__ rowsA,
    const float* __restrict__ zin_base, int use_g,
    float* __restrict__ zout,
    int G, int k, int row_groups) {
  __shared__ float wbuf[4][64];
  __shared__ int   cbuf[4][64];
  __shared__ int   rbuf[4][64];
  int c = blockIdx.x / row_groups, rg = blockIdx.x % row_groups;
  int f = c / G, g = c - f * G;
  int wave = threadIdx.x >> 6, lane = threadIdx.x & 63;
  const float* zin = zin_base + ((size_t)(use_g ? g : c) << 15);
  float* zo = zout + ((size_t)c << 15);
  const float* W = nullptr;
  if (Wdense) W = Wdense + (((size_t)((f * 3 + k) * G + g)) << 18);
  int rows_per_wg = NN / row_groups;
  int rpw = rows_per_wg >> 2;
  int r0 = rg * rows_per_wg + wave * rpw, r1 = r0 + rpw;
  int jb = row_ptr[r0], je = row_ptr[r1];
  float acc = 0.f; int r = r0;
  for (int j0 = jb; j0 < je; j0 += 64) {
    int j = j0 + lane;
    float wv = 0.f; int cv = 0, rv = r1 - 1;
    if (j < je) {
      cv = cols[j]; rv = rowsA[j];
      wv = Wdense ? W[((size_t)rv << 9) + cv] : svals[j];   // 64-wide scattered gather
    }
    wbuf[wave][lane] = wv; cbuf[wave][lane] = cv; rbuf[wave][lane] = rv;
    for (int l0 = 0; l0 < 64; l0 += 8) {
      float v8[8], w8[8]; int r8[8];
#pragma unroll
      for (int i = 0; i < 8; ++i) {
        int cc = cbuf[wave][l0 + i];
        w8[i] = wbuf[wave][l0 + i];
        r8[i] = rbuf[wave][l0 + i];
        v8[i] = zin[((size_t)cc << 6) + lane];              // 256B coalesced, L2-resident
      }
#pragma unroll
      for (int i = 0; i < 8; ++i) {
        if (r8[i] != r) {
          do { zo[((size_t)r << 6) + lane] = acc; acc = 0.f; ++r; } while (r < r8[i]);
        }
        acc += w8[i] * v8[i];
      }
    }
  }
  while (r < r1) { zo[((size_t)r << 6) + lane] = acc; acc = 0.f; ++r; }
}

// ---------------- layer combines ----------------
__global__ __launch_bounds__(256) void k_y1(const float* __restrict__ z0,
    const float* __restrict__ z1, const float* __restrict__ z2,
    const float* __restrict__ xt, const float* __restrict__ u1, const float* __restrict__ u2,
    const float* __restrict__ wLSI1, const float* __restrict__ b1, float* __restrict__ y1) {
  int tid = blockIdx.x * 256 + threadIdx.x;   // 0..262143
  int f = tid >> 15, mb = tid & (NB - 1);
  float r = z0[tid] + z1[tid] + z2[tid];
  r += wLSI1[f * 3 + 0] * xt[mb] + wLSI1[f * 3 + 1] * u1[mb] + wLSI1[f * 3 + 2] * u2[mb];
  y1[tid] = r + b1[f];
}

__global__ __launch_bounds__(256) void k_y2(const float* __restrict__ z0,
    const float* __restrict__ z1, const float* __restrict__ z2,
    const float* __restrict__ y1, const float* __restrict__ v1, const float* __restrict__ v2,
    const float* __restrict__ wLSI2, const float* __restrict__ b2, float* __restrict__ y2) {
  int tid = blockIdx.x * 256 + threadIdx.x;   // 0..262143
  int f = tid >> 15, mb = tid & (NB - 1);
  float r = b2[f];
#pragma unroll
  for (int g = 0; g < 8; ++g) {
    size_t zc = ((size_t)(f * 8 + g) << 15) + mb;
    r += z0[zc] + z1[zc] + z2[zc];
    size_t gc = ((size_t)g << 15) + mb;
    r += wLSI2[f * 24 + g] * y1[gc] + wLSI2[f * 24 + 8 + g] * v1[gc] + wLSI2[f * 24 + 16 + g] * v2[gc];
  }
  y2[tid] = r;
}

// ---------------- readout GEMMs ----------------
__global__ __launch_bounds__(256) void k_init_ht(const float* __restrict__ bW1,
                                                 float* __restrict__ ht) {
  int tid = blockIdx.x * 256 + threadIdx.x;   // 0..32767
  ht[tid] = bW1[tid >> 6];
}

// h[p][b] += sum_q W1[p,q] * y2flat[q][b];  wave: 8 p's x 512-q slice, atomic reduce
__global__ __launch_bounds__(256) void k_gemm1(const float* __restrict__ W1,
                                               const float* __restrict__ y2,
                                               float* __restrict__ ht) {
  int wid = (blockIdx.x * 256 + threadIdx.x) >> 6;  // 0..511
  int lane = threadIdx.x & 63;
  int pg = wid >> 3;             // p-group 0..63 (8 p's each)
  int q0 = (wid & 7) << 9;       // q slice of 512
  float acc[8] = {0, 0, 0, 0, 0, 0, 0, 0};
  const float* Wp = W1 + (size_t)(pg * 8) * 4096;
  for (int q = q0; q < q0 + 512; q += 4) {
#pragma unroll
    for (int u = 0; u < 4; ++u) {
      float v = y2[(size_t)(q + u) * 64 + lane];
#pragma unroll
      for (int p = 0; p < 8; ++p) acc[p] += Wp[(size_t)p * 4096 + q + u] * v;
    }
  }
#pragma unroll
  for (int p = 0; p < 8; ++p) atomicAdd(&ht[(size_t)(pg * 8 + p) * 64 + lane], acc[p]);
}

__global__ __launch_bounds__(256) void k_gemm2(const float* __restrict__ W2,
                                               const float* __restrict__ bW2,
                                               const float* __restrict__ ht,
                                               float* __restrict__ out) {
  int wid = (blockIdx.x * 256 + threadIdx.x) >> 6;  // 0..127 = output feature o
  int lane = threadIdx.x & 63;                      // batch b
  float acc = 0.f;
  for (int p = 0; p < 512; p += 4) {
#pragma unroll
    for (int u = 0; u < 4; ++u) acc += W2[(size_t)wid * 512 + p + u] * ht[(size_t)(p + u) * 64 + lane];
  }
  out[(size_t)lane * 128 + wid] = acc + bW2[wid];
}

extern "C" void kernel_launch(void* const* d_in, const int* in_sizes, int n_in,
                              void* d_out, int out_size, void* d_ws, size_t ws_size,
                              hipStream_t stream) {
  const float* x     = (const float*)d_in[0];
  const float* S     = (const float*)d_in[1];
  const float* wEV1  = (const float*)d_in[2];
  const float* wLSI1 = (const float*)d_in[3];
  const float* b1    = (const float*)d_in[4];
  const float* wEV2  = (const float*)d_in[5];
  const float* wLSI2 = (const float*)d_in[6];
  const float* b2    = (const float*)d_in[7];
  const float* W1    = (const float*)d_in[8];
  const float* bW1   = (const float*)d_in[9];
  const float* W2    = (const float*)d_in[10];
  const float* bW2   = (const float*)d_in[11];
  float* out = (float*)d_out;

  char* w = (char*)d_ws;
  auto alloc = [&](size_t bytes) { char* p = w; w += (bytes + 255) & ~(size_t)255; return p; };
  int*   sp_cnt  = (int*)alloc(512 * 4);
  int*   s_cnt   = (int*)alloc(512 * 4);
  int*   sp_ptr  = (int*)alloc(513 * 4);
  int*   s_ptr   = (int*)alloc(513 * 4);
  int*   sp_cols = (int*)alloc(CAP * 4);
  int*   sp_rows = (int*)alloc(CAP * 4);
  int*   s_cols  = (int*)alloc(CAP * 4);
  int*   s_rows  = (int*)alloc(CAP * 4);
  float* s_vals  = (float*)alloc(CAP * 4);
  float* xt      = (float*)alloc((size_t)NB * 4);
  float* u1      = (float*)alloc((size_t)NB * 4);
  float* u2      = (float*)alloc((size_t)NB * 4);
  float* y1      = (float*)alloc((size_t)8 * NB * 4);
  float* v1      = (float*)alloc((size_t)8 * NB * 4);
  float* v2      = (float*)alloc((size_t)8 * NB * 4);
  float* y2      = (float*)alloc((size_t)8 * NB * 4);
  float* ht      = (float*)alloc((size_t)NB * 4);
  float* z0      = (float*)alloc((size_t)64 * NB * 4);
  float* z1      = (float*)alloc((size_t)64 * NB * 4);
  float* z2      = (float*)alloc((size_t)64 * NB * 4);
  (void)ws_size; (void)in_sizes; (void)n_in; (void)out_size;

  // CSR build (pattern sp and S-values), deterministic two-pass
  k_csr_count<<<128, 256, 0, stream>>>(S, sp_cnt, s_cnt);
  k_prefix<<<1, 64, 0, stream>>>(sp_ptr, s_ptr, sp_cnt, s_cnt);
  k_csr_fill<<<128, 256, 0, stream>>>(S, sp_ptr, s_ptr, sp_cols, sp_rows, s_cols, s_rows, s_vals);
  k_transpose<<<128, 256, 0, stream>>>(x, xt);

  // ---- layer 1 ----
  // EV chains: 8 (f), G=1, row_groups=32 -> grid 256
  k_ev_step<<<256, 256, 0, stream>>>(wEV1, nullptr, sp_ptr, sp_cols, sp_rows, xt, 1, z0, 1, 0, 32);
  k_ev_step<<<256, 256, 0, stream>>>(wEV1, nullptr, sp_ptr, sp_cols, sp_rows, z0, 0, z1, 1, 1, 32);
  k_ev_step<<<256, 256, 0, stream>>>(wEV1, nullptr, sp_ptr, sp_cols, sp_rows, z1, 0, z2, 1, 2, 32);
  // LSI shift chain: u1 = S x, u2 = S u1 (chains=1, row_groups=128)
  k_ev_step<<<128, 256, 0, stream>>>(nullptr, s_vals, s_ptr, s_cols, s_rows, xt, 1, u1, 1, 0, 128);
  k_ev_step<<<128, 256, 0, stream>>>(nullptr, s_vals, s_ptr, s_cols, s_rows, u1, 0, u2, 1, 0, 128);
  k_y1<<<1024, 256, 0, stream>>>(z0, z1, z2, xt, u1, u2, wLSI1, b1, y1);

  // ---- layer 2 ----
  // EV chains: 64 (f,g), G=8, row_groups=8 -> grid 512
  k_ev_step<<<512, 256, 0, stream>>>(wEV2, nullptr, sp_ptr, sp_cols, sp_rows, y1, 1, z0, 8, 0, 8);
  k_ev_step<<<512, 256, 0, stream>>>(wEV2, nullptr, sp_ptr, sp_cols, sp_rows, z0, 0, z1, 8, 1, 8);
  k_ev_step<<<512, 256, 0, stream>>>(wEV2, nullptr, sp_ptr, sp_cols, sp_rows, z1, 0, z2, 8, 2, 8);
  // LSI shift chains: v1 = S y1, v2 = S v1 (chains=8, row_groups=32)
  k_ev_step<<<256, 256, 0, stream>>>(nullptr, s_vals, s_ptr, s_cols, s_rows, y1, 1, v1, 8, 0, 32);
  k_ev_step<<<256, 256, 0, stream>>>(nullptr, s_vals, s_ptr, s_cols, s_rows, v1, 0, v2, 8, 0, 32);
  k_y2<<<1024, 256, 0, stream>>>(z0, z1, z2, y1, v1, v2, wLSI2, b2, y2);

  // ---- readout ----
  k_init_ht<<<128, 256, 0, stream>>>(bW1, ht);
  k_gemm1<<<128, 256, 0, stream>>>(W1, y2, ht);
  k_gemm2<<<32, 256, 0, stream>>>(W2, bW2, ht, out);
}